// Round 1
// 368.194 us; speedup vs baseline: 1.1445x; 1.1445x over previous
//
#include <hip/hip_runtime.h>
#include <hip/hip_bf16.h>
#include <cmath>
#include <cstdint>

// R1: 256x256-tile, 8-wave, 4-deep counted-vmcnt pipelined bf16 MFMA GEMM
// (T2 st_16x32 LDS swizzle + T3/T4 counted vmcnt(8), raw s_barrier 1/K-tile
//  + T5 setprio) replacing the m97 128x128 2-barrier structure.
//
// Schedule invariants (soundness of the counted waits):
//  - 4 LDS buffers of 32 KB (A 256x32 bf16 + B 256x32 bf16), tile t -> buf t&3.
//  - iteration t: wait vmcnt(8) [leaves tiles t+1,t+2 in flight -> tile t
//    retired, vmcnt retires in order], s_barrier => tile t resident for ALL
//    waves; then stage tile t+3 into buf (t+3)&3 (last read at iter t-1,
//    all waves past that barrier); then ds_read + 32 MFMA from buf t&3.
//  - ds_reads are fully consumed by MFMAs before the next barrier (compiler
//    lgkm waits), so no pending LDS reads cross a barrier.
//  - tail: vmcnt(4) at t=nt-2, vmcnt(0) at t=nt-1.
// LDS swizzle: rows of 32 bf16 (64 B); phys_byte = log_byte ^ ((log>>9&1)<<5)
//  => read col ^= 16 (u16) when row&8; global_load_lds writes linearly, so the
//  per-lane GLOBAL source col is pre-swizzled with the same involution
//  (scol ^= 16 for lanes 32..63, whose dest rows have bit3 set).

#define AS1 __attribute__((address_space(1)))
#define AS3 __attribute__((address_space(3)))

typedef unsigned short u16;
typedef __bf16 bf16x8 __attribute__((ext_vector_type(8)));
typedef float f32x4 __attribute__((ext_vector_type(4)));
typedef unsigned short u16x4 __attribute__((ext_vector_type(4)));

#define BM 256
#define BN 256
#define BK 32
#define NBUF 4
// per-buf: A region 256*32 u16 (8192), B region 8192 -> buf stride 16384 u16

__device__ __forceinline__ u16 f2bf_rne(float f) {
  uint32_t u = __float_as_uint(f);
  u += 0x7FFFu + ((u >> 16) & 1u);
  return (u16)(u >> 16);
}

// activation ternary -> bf16 bits of {-0.5, 0, +0.5}
__device__ __forceinline__ u16 ter_x(float v) {
  double d = (double)v;
  return d > 0.33 ? (u16)0x3F00u : (d < -0.33 ? (u16)0xBF00u : (u16)0u);
}

// weight ternary -> fp32 {-0.6, 0, +0.6}
__device__ __forceinline__ float ter_w(float v) {
  double d = (double)v;
  return d > 0.2 ? 0.6f : (d < -0.2 ? -0.6f : 0.0f);
}

__global__ void quant_x_kernel(const float* __restrict__ x, u16* __restrict__ xq,
                               long n4) {
  long i = (long)blockIdx.x * blockDim.x + threadIdx.x;
  if (i >= n4) return;
  float4 v = ((const float4*)x)[i];
  u16x4 q;
  q.x = ter_x(v.x); q.y = ter_x(v.y); q.z = ter_x(v.z); q.w = ter_x(v.w);
  ((u16x4*)xq)[i] = q;
}

__global__ void quant_w_kernel(const float* __restrict__ w,
                               const float* __restrict__ rr,
                               u16* __restrict__ wq, long n4) {
  long i = (long)blockIdx.x * blockDim.x + threadIdx.x;
  if (i >= n4) return;
  float4 a = ((const float4*)w)[i];
  float4 b = ((const float4*)rr)[i];
  u16x4 q;
  q.x = f2bf_rne(ter_w(a.x) + b.x);
  q.y = f2bf_rne(ter_w(a.y) + b.y);
  q.z = f2bf_rne(ter_w(a.z) + b.z);
  q.w = f2bf_rne(ter_w(a.w) + b.w);
  ((u16x4*)wq)[i] = q;
}

// async 16B/lane global->LDS; LDS dest is wave-uniform base + lane*16
__device__ __forceinline__ void gld_lds16(const void* g, void* l) {
  __builtin_amdgcn_global_load_lds((AS1 void*)g, (AS3 void*)l, 16, 0, 0);
}

// C[m][n] = sum_k A[m][k] * B[n][k]  (both K-contiguous bf16; C fp32)
// Requires M%256==0, N%256==0, K%32==0, K/32>=4.
__global__ __launch_bounds__(512, 2) void gemm256_kernel(
    const u16* __restrict__ Aq, const u16* __restrict__ Bq,
    float* __restrict__ C, int M, int N, int K) {
  __shared__ u16 lds[NBUF * 16384];  // 128 KiB

  const int tid  = threadIdx.x;
  const int wid  = tid >> 6;
  const int lane = tid & 63;
  const int wm = wid >> 2;   // 0..1  (rows: wm*128)
  const int wn = wid & 3;    // 0..3  (cols: wn*64)

  const int m0 = blockIdx.y * BM;
  const int n0 = blockIdx.x * BN;

  // ---- staging addressing: per slot (2/region), wave covers 16 rows of 64B
  const int srow = wid * 16 + (lane >> 2);                    // 0..127 (+128 slot1)
  const int scol = ((lane & 3) * 8) ^ ((lane & 32) ? 16 : 0); // pre-swizzled src col
  const u16* pa = Aq + (size_t)(m0 + srow) * K + scol;
  const u16* pb = Bq + (size_t)(n0 + srow) * K + scol;
  const size_t slot1 = (size_t)128 * K;
  const int sd = wid * 512;  // wave's u16 offset within a region slot

  // ---- fragment read addressing (swizzled) ----
  const int fr  = lane & 15;
  const int fk  = (lane >> 4) * 8;
  const int col = fk ^ ((fr & 8) ? 16 : 0);
  const int aoff = (wm * 128 + fr) * 32 + col;         // + mt*512
  const int boff = 8192 + (wn * 64 + fr) * 32 + col;   // + ntl*512

  f32x4 acc[8][4] = {};
  const int nt = K / BK;

  // prologue: stage tiles 0..2 (12 loads/wave in flight)
#pragma unroll
  for (int T = 0; T < 3; ++T) {
    const int bb = T * 16384;
    const u16* at = pa + (size_t)T * BK;
    const u16* bt = pb + (size_t)T * BK;
    gld_lds16(at,         &lds[bb + sd]);
    gld_lds16(at + slot1, &lds[bb + sd + 4096]);
    gld_lds16(bt,         &lds[bb + 8192 + sd]);
    gld_lds16(bt + slot1, &lds[bb + 8192 + sd + 4096]);
  }

  for (int t = 0; t < nt; ++t) {
    // counted drain: tile t retired; tiles t+1..t+3 stay in flight
    if (t < nt - 2)       asm volatile("s_waitcnt vmcnt(8)" ::: "memory");
    else if (t == nt - 2) asm volatile("s_waitcnt vmcnt(4)" ::: "memory");
    else                  asm volatile("s_waitcnt vmcnt(0)" ::: "memory");
    __builtin_amdgcn_sched_barrier(0);
    __builtin_amdgcn_s_barrier();
    __builtin_amdgcn_sched_barrier(0);

    const int Tn = t + 3;
    if (Tn < nt) {
      const int bb = (Tn & 3) * 16384;
      const u16* at = pa + (size_t)Tn * BK;
      const u16* bt = pb + (size_t)Tn * BK;
      gld_lds16(at,         &lds[bb + sd]);
      gld_lds16(at + slot1, &lds[bb + sd + 4096]);
      gld_lds16(bt,         &lds[bb + 8192 + sd]);
      gld_lds16(bt + slot1, &lds[bb + 8192 + sd + 4096]);
    }

    const int rb = (t & 3) * 16384;
    bf16x8 a[8], b[4];
#pragma unroll
    for (int i = 0; i < 8; ++i) a[i] = *(const bf16x8*)&lds[rb + aoff + i * 512];
#pragma unroll
    for (int j = 0; j < 4; ++j) b[j] = *(const bf16x8*)&lds[rb + boff + j * 512];

    __builtin_amdgcn_s_setprio(1);
#pragma unroll
    for (int i = 0; i < 8; ++i)
#pragma unroll
      for (int j = 0; j < 4; ++j)
        acc[i][j] =
            __builtin_amdgcn_mfma_f32_16x16x32_bf16(a[i], b[j], acc[i][j], 0, 0, 0);
    __builtin_amdgcn_s_setprio(0);
  }

  // C/D layout: row = (lane>>4)*4 + reg, col = lane&15  [measured m89/m91]
  const int om = m0 + wm * 128 + (lane >> 4) * 4;
  const int on = n0 + wn * 64 + (lane & 15);
#pragma unroll
  for (int i = 0; i < 8; ++i)
#pragma unroll
    for (int j = 0; j < 4; ++j)
#pragma unroll
      for (int r = 0; r < 4; ++r)
        C[(size_t)(om + i * 16 + r) * N + (on + j * 16)] = acc[i][j][r];
}

// ---- fallback (workspace too small): old fused 128x128 kernel, verified R0 ----
__global__ __launch_bounds__(256) void gemm_fused128_kernel(
    const float* __restrict__ Xf, const u16* __restrict__ Bq,
    float* __restrict__ C, int M, int N, int K) {
  __shared__ u16 As[128 * 64];
  __shared__ u16 Bs[128 * 64];

  const int tid  = threadIdx.x;
  const int wid  = tid >> 6;
  const int lane = tid & 63;
  const int m0 = blockIdx.y * 128;
  const int n0 = blockIdx.x * 128;
  const int r8 = lane >> 3;
  const int c8 = (lane & 7) * 8;
  const int mw = (wid >> 1) * 64;
  const int nw = (wid & 1) * 64;
  const int fr = lane & 15;
  const int fk = (lane >> 4) * 8;

  f32x4 acc[4][4] = {};

  for (int k0 = 0; k0 < K; k0 += 64) {
#pragma unroll
    for (int t = 0; t < 4; ++t) {
      const int rbase = wid * 32 + t * 8;
      gld_lds16(Bq + (size_t)(n0 + rbase + r8) * K + k0 + c8, &Bs[rbase * 64]);
    }
#pragma unroll
    for (int it = 0; it < 8; ++it) {
      const int idx = it * 256 + tid;
      const int row = idx >> 4;
      const int c4  = (idx & 15) * 4;
      const float4 v = *(const float4*)&Xf[(size_t)(m0 + row) * K + k0 + c4];
      u16x4 q;
      q.x = ter_x(v.x); q.y = ter_x(v.y); q.z = ter_x(v.z); q.w = ter_x(v.w);
      *(u16x4*)&As[row * 64 + c4] = q;
    }
    __syncthreads();

#pragma unroll
    for (int kk = 0; kk < 64; kk += 32) {
      bf16x8 a[4], b[4];
#pragma unroll
      for (int i = 0; i < 4; ++i)
        a[i] = *(const bf16x8*)&As[(mw + i * 16 + fr) * 64 + kk + fk];
#pragma unroll
      for (int j = 0; j < 4; ++j)
        b[j] = *(const bf16x8*)&Bs[(nw + j * 16 + fr) * 64 + kk + fk];
#pragma unroll
      for (int i = 0; i < 4; ++i)
#pragma unroll
        for (int j = 0; j < 4; ++j)
          acc[i][j] =
              __builtin_amdgcn_mfma_f32_16x16x32_bf16(a[i], b[j], acc[i][j], 0, 0, 0);
    }
    __syncthreads();
  }

  const int om = m0 + mw + (lane >> 4) * 4;
  const int on = n0 + nw + (lane & 15);
#pragma unroll
  for (int i = 0; i < 4; ++i)
#pragma unroll
    for (int j = 0; j < 4; ++j)
#pragma unroll
      for (int r = 0; r < 4; ++r)
        C[(size_t)(om + i * 16 + r) * N + (on + j * 16)] = acc[i][j][r];
}

extern "C" void kernel_launch(void* const* d_in, const int* in_sizes, int n_in,
                              void* d_out, int out_size, void* d_ws, size_t ws_size,
                              hipStream_t stream) {
  const float* x  = (const float*)d_in[0];
  const float* w  = (const float*)d_in[1];
  const float* rr = (const float*)d_in[2];
  float* out = (float*)d_out;

  const long xn = (long)in_sizes[0];
  const long wn = (long)in_sizes[1];
  const int K = (int)llround(std::sqrt((double)wn));  // weight is [D,D]
  const int N = K;
  const int M = (int)(xn / K);

  u16* wq = (u16*)d_ws;
  u16* xq = (u16*)d_ws + (size_t)N * K;
  const size_t need = ((size_t)M * K + (size_t)N * K) * sizeof(u16);

  {
    long n4 = wn / 4;
    quant_w_kernel<<<(int)((n4 + 255) / 256), 256, 0, stream>>>(w, rr, wq, n4);
  }

  const bool ok256 = (M % BM == 0) && (N % BN == 0) && (K % BK == 0) &&
                     (K / BK >= 4) && (ws_size >= need);
  if (ok256) {
    long n4 = xn / 4;
    quant_x_kernel<<<(int)((n4 + 255) / 256), 256, 0, stream>>>(x, xq, n4);
    dim3 grid(N / BN, M / BM);
    gemm256_kernel<<<grid, 512, 0, stream>>>(xq, wq, out, M, N, K);
  } else {
    dim3 grid(N / 128, M / 128);
    gemm_fused128_kernel<<<grid, 256, 0, stream>>>(x, wq, out, M, N, K);
  }
}

// Round 3
// 363.270 us; speedup vs baseline: 1.1600x; 1.0136x over previous
//
#include <hip/hip_runtime.h>
#include <hip/hip_bf16.h>
#include <cmath>
#include <cstdint>

// R3 (= R2 resubmit; round-2 bench was an infra failure, no data):
// 256x256-tile, 8-wave, 4-deep counted-vmcnt pipeline (R1, verified) with
// the K-iter compute split into TWO phases (m201 barrier rate: 1 barrier/16-K):
//   phase A: issue ds_read a0..3+b0..3, stage A-region of tile t+3,
//            lgkmcnt(0), 16 MFMA (m-half 0)
//   mid s_barrier
//   phase B: issue ds_read a4..7, stage B-region, lgkmcnt(0),
//            16 MFMA (m-half 1)
// Mechanism: half-sized LDS read bursts overlap the other phase's MFMA drain
// across waves (T3 fine interleave); counted vmcnt (T4) and st_16x32 swizzle
// (T2, bank-conflict=0 measured R1) unchanged; T5 setprio around each cluster.
//
// Race invariants (audited again R2->R3):
//  - every ds_read of buf t is consumed by an MFMA before the wave reaches
//    iter t+1's top barrier (lgkmcnt(0) per phase) -> no pending reads cross it
//  - phase-A staging writes buf (t+3)&3 = (t-1)&3; last reads of that buffer
//    (iter t-1 phase B) were drained by that phase's lgkmcnt(0) before every
//    wave crossed iter t's top barrier, which precedes this staging
//  - vmcnt(8) at iter top -> tile t's 4 loads retired, t+1..t+3 in flight;
//    tail: exactly 8 outstanding at t=nt-3 (wait is no-op-safe), then 4 -> 0
//  - both barriers unconditional for all 8 waves -> no barrier divergence.

#define AS1 __attribute__((address_space(1)))
#define AS3 __attribute__((address_space(3)))

typedef unsigned short u16;
typedef __bf16 bf16x8 __attribute__((ext_vector_type(8)));
typedef float f32x4 __attribute__((ext_vector_type(4)));
typedef unsigned short u16x4 __attribute__((ext_vector_type(4)));

#define BM 256
#define BN 256
#define BK 32
#define NBUF 4
// per-buf: A region 256*32 u16 (8192), B region 8192 -> buf stride 16384 u16

__device__ __forceinline__ u16 f2bf_rne(float f) {
  uint32_t u = __float_as_uint(f);
  u += 0x7FFFu + ((u >> 16) & 1u);
  return (u16)(u >> 16);
}

// activation ternary -> bf16 bits of {-0.5, 0, +0.5}
__device__ __forceinline__ u16 ter_x(float v) {
  double d = (double)v;
  return d > 0.33 ? (u16)0x3F00u : (d < -0.33 ? (u16)0xBF00u : (u16)0u);
}

// weight ternary -> fp32 {-0.6, 0, +0.6}
__device__ __forceinline__ float ter_w(float v) {
  double d = (double)v;
  return d > 0.2 ? 0.6f : (d < -0.2 ? -0.6f : 0.0f);
}

__global__ void quant_x_kernel(const float* __restrict__ x, u16* __restrict__ xq,
                               long n4) {
  long i = (long)blockIdx.x * blockDim.x + threadIdx.x;
  if (i >= n4) return;
  float4 v = ((const float4*)x)[i];
  u16x4 q;
  q.x = ter_x(v.x); q.y = ter_x(v.y); q.z = ter_x(v.z); q.w = ter_x(v.w);
  ((u16x4*)xq)[i] = q;
}

__global__ void quant_w_kernel(const float* __restrict__ w,
                               const float* __restrict__ rr,
                               u16* __restrict__ wq, long n4) {
  long i = (long)blockIdx.x * blockDim.x + threadIdx.x;
  if (i >= n4) return;
  float4 a = ((const float4*)w)[i];
  float4 b = ((const float4*)rr)[i];
  u16x4 q;
  q.x = f2bf_rne(ter_w(a.x) + b.x);
  q.y = f2bf_rne(ter_w(a.y) + b.y);
  q.z = f2bf_rne(ter_w(a.z) + b.z);
  q.w = f2bf_rne(ter_w(a.w) + b.w);
  ((u16x4*)wq)[i] = q;
}

// async 16B/lane global->LDS; LDS dest is wave-uniform base + lane*16
__device__ __forceinline__ void gld_lds16(const void* g, void* l) {
  __builtin_amdgcn_global_load_lds((AS1 void*)g, (AS3 void*)l, 16, 0, 0);
}

// C[m][n] = sum_k A[m][k] * B[n][k]  (both K-contiguous bf16; C fp32)
// Requires M%256==0, N%256==0, K%32==0, K/32>=4.
__global__ __launch_bounds__(512, 2) void gemm256_kernel(
    const u16* __restrict__ Aq, const u16* __restrict__ Bq,
    float* __restrict__ C, int M, int N, int K) {
  __shared__ u16 lds[NBUF * 16384];  // 128 KiB

  const int tid  = threadIdx.x;
  const int wid  = tid >> 6;
  const int lane = tid & 63;
  const int wm = wid >> 2;   // 0..1  (rows: wm*128)
  const int wn = wid & 3;    // 0..3  (cols: wn*64)

  const int m0 = blockIdx.y * BM;
  const int n0 = blockIdx.x * BN;

  // ---- staging addressing: per slot (2/region), wave covers 16 rows of 64B
  const int srow = wid * 16 + (lane >> 2);                    // 0..127 (+128 slot1)
  const int scol = ((lane & 3) * 8) ^ ((lane & 32) ? 16 : 0); // pre-swizzled src col
  const u16* pa = Aq + (size_t)(m0 + srow) * K + scol;
  const u16* pb = Bq + (size_t)(n0 + srow) * K + scol;
  const size_t slot1 = (size_t)128 * K;
  const int sd = wid * 512;  // wave's u16 offset within a region slot

  // ---- fragment read addressing (swizzled) ----
  const int fr  = lane & 15;
  const int fk  = (lane >> 4) * 8;
  const int col = fk ^ ((fr & 8) ? 16 : 0);
  const int aoff = (wm * 128 + fr) * 32 + col;         // + mt*512
  const int boff = 8192 + (wn * 64 + fr) * 32 + col;   // + ntl*512

  f32x4 acc[8][4] = {};
  const int nt = K / BK;

  // prologue: stage tiles 0..2 (12 loads/wave in flight)
#pragma unroll
  for (int T = 0; T < 3; ++T) {
    const int bb = T * 16384;
    const u16* at = pa + (size_t)T * BK;
    const u16* bt = pb + (size_t)T * BK;
    gld_lds16(at,         &lds[bb + sd]);
    gld_lds16(at + slot1, &lds[bb + sd + 4096]);
    gld_lds16(bt,         &lds[bb + 8192 + sd]);
    gld_lds16(bt + slot1, &lds[bb + 8192 + sd + 4096]);
  }

  for (int t = 0; t < nt; ++t) {
    // counted drain: tile t retired; tiles t+1..t+3 stay in flight
    if (t < nt - 2)       asm volatile("s_waitcnt vmcnt(8)" ::: "memory");
    else if (t == nt - 2) asm volatile("s_waitcnt vmcnt(4)" ::: "memory");
    else                  asm volatile("s_waitcnt vmcnt(0)" ::: "memory");
    __builtin_amdgcn_sched_barrier(0);
    __builtin_amdgcn_s_barrier();
    __builtin_amdgcn_sched_barrier(0);

    const int rb = (t & 3) * 16384;
    const int Tn = t + 3;
    const int bb = (Tn & 3) * 16384;
    const u16* at = pa + (size_t)Tn * BK;
    const u16* bt = pb + (size_t)Tn * BK;

    bf16x8 a[8], b[4];

    // ---------- phase A: reads a0..3 + b0..3, stage A-region ----------
#pragma unroll
    for (int i = 0; i < 4; ++i) a[i] = *(const bf16x8*)&lds[rb + aoff + i * 512];
#pragma unroll
    for (int j = 0; j < 4; ++j) b[j] = *(const bf16x8*)&lds[rb + boff + j * 512];
    if (Tn < nt) {
      gld_lds16(at,         &lds[bb + sd]);
      gld_lds16(at + slot1, &lds[bb + sd + 4096]);
    }
    asm volatile("s_waitcnt lgkmcnt(0)" ::: "memory");
    __builtin_amdgcn_sched_barrier(0);
    __builtin_amdgcn_s_setprio(1);
#pragma unroll
    for (int i = 0; i < 4; ++i)
#pragma unroll
      for (int j = 0; j < 4; ++j)
        acc[i][j] =
            __builtin_amdgcn_mfma_f32_16x16x32_bf16(a[i], b[j], acc[i][j], 0, 0, 0);
    __builtin_amdgcn_s_setprio(0);
    __builtin_amdgcn_sched_barrier(0);
    __builtin_amdgcn_s_barrier();
    __builtin_amdgcn_sched_barrier(0);

    // ---------- phase B: reads a4..7, stage B-region ----------
#pragma unroll
    for (int i = 4; i < 8; ++i) a[i] = *(const bf16x8*)&lds[rb + aoff + i * 512];
    if (Tn < nt) {
      gld_lds16(bt,         &lds[bb + 8192 + sd]);
      gld_lds16(bt + slot1, &lds[bb + 8192 + sd + 4096]);
    }
    asm volatile("s_waitcnt lgkmcnt(0)" ::: "memory");
    __builtin_amdgcn_sched_barrier(0);
    __builtin_amdgcn_s_setprio(1);
#pragma unroll
    for (int i = 4; i < 8; ++i)
#pragma unroll
      for (int j = 0; j < 4; ++j)
        acc[i][j] =
            __builtin_amdgcn_mfma_f32_16x16x32_bf16(a[i], b[j], acc[i][j], 0, 0, 0);
    __builtin_amdgcn_s_setprio(0);
    __builtin_amdgcn_sched_barrier(0);
  }

  // C/D layout: row = (lane>>4)*4 + reg, col = lane&15  [measured m89/m91]
  const int om = m0 + wm * 128 + (lane >> 4) * 4;
  const int on = n0 + wn * 64 + (lane & 15);
#pragma unroll
  for (int i = 0; i < 8; ++i)
#pragma unroll
    for (int j = 0; j < 4; ++j)
#pragma unroll
      for (int r = 0; r < 4; ++r)
        C[(size_t)(om + i * 16 + r) * N + (on + j * 16)] = acc[i][j][r];
}

// ---- fallback (workspace too small): old fused 128x128 kernel, verified R0 ----
__global__ __launch_bounds__(256) void gemm_fused128_kernel(
    const float* __restrict__ Xf, const u16* __restrict__ Bq,
    float* __restrict__ C, int M, int N, int K) {
  __shared__ u16 As[128 * 64];
  __shared__ u16 Bs[128 * 64];

  const int tid  = threadIdx.x;
  const int wid  = tid >> 6;
  const int lane = tid & 63;
  const int m0 = blockIdx.y * 128;
  const int n0 = blockIdx.x * 128;
  const int r8 = lane >> 3;
  const int c8 = (lane & 7) * 8;
  const int mw = (wid >> 1) * 64;
  const int nw = (wid & 1) * 64;
  const int fr = lane & 15;
  const int fk = (lane >> 4) * 8;

  f32x4 acc[4][4] = {};

  for (int k0 = 0; k0 < K; k0 += 64) {
#pragma unroll
    for (int t = 0; t < 4; ++t) {
      const int rbase = wid * 32 + t * 8;
      gld_lds16(Bq + (size_t)(n0 + rbase + r8) * K + k0 + c8, &Bs[rbase * 64]);
    }
#pragma unroll
    for (int it = 0; it < 8; ++it) {
      const int idx = it * 256 + tid;
      const int row = idx >> 4;
      const int c4  = (idx & 15) * 4;
      const float4 v = *(const float4*)&Xf[(size_t)(m0 + row) * K + k0 + c4];
      u16x4 q;
      q.x = ter_x(v.x); q.y = ter_x(v.y); q.z = ter_x(v.z); q.w = ter_x(v.w);
      *(u16x4*)&As[row * 64 + c4] = q;
    }
    __syncthreads();

#pragma unroll
    for (int kk = 0; kk < 64; kk += 32) {
      bf16x8 a[4], b[4];
#pragma unroll
      for (int i = 0; i < 4; ++i)
        a[i] = *(const bf16x8*)&As[(mw + i * 16 + fr) * 64 + kk + fk];
#pragma unroll
      for (int j = 0; j < 4; ++j)
        b[j] = *(const bf16x8*)&Bs[(nw + j * 16 + fr) * 64 + kk + fk];
#pragma unroll
      for (int i = 0; i < 4; ++i)
#pragma unroll
        for (int j = 0; j < 4; ++j)
          acc[i][j] =
              __builtin_amdgcn_mfma_f32_16x16x32_bf16(a[i], b[j], acc[i][j], 0, 0, 0);
    }
    __syncthreads();
  }

  const int om = m0 + mw + (lane >> 4) * 4;
  const int on = n0 + nw + (lane & 15);
#pragma unroll
  for (int i = 0; i < 4; ++i)
#pragma unroll
    for (int j = 0; j < 4; ++j)
#pragma unroll
      for (int r = 0; r < 4; ++r)
        C[(size_t)(om + i * 16 + r) * N + (on + j * 16)] = acc[i][j][r];
}

extern "C" void kernel_launch(void* const* d_in, const int* in_sizes, int n_in,
                              void* d_out, int out_size, void* d_ws, size_t ws_size,
                              hipStream_t stream) {
  const float* x  = (const float*)d_in[0];
  const float* w  = (const float*)d_in[1];
  const float* rr = (const float*)d_in[2];
  float* out = (float*)d_out;

  const long xn = (long)in_sizes[0];
  const long wn = (long)in_sizes[1];
  const int K = (int)llround(std::sqrt((double)wn));  // weight is [D,D]
  const int N = K;
  const int M = (int)(xn / K);

  u16* wq = (u16*)d_ws;
  u16* xq = (u16*)d_ws + (size_t)N * K;
  const size_t need = ((size_t)M * K + (size_t)N * K) * sizeof(u16);

  {
    long n4 = wn / 4;
    quant_w_kernel<<<(int)((n4 + 255) / 256), 256, 0, stream>>>(w, rr, wq, n4);
  }

  const bool ok256 = (M % BM == 0) && (N % BN == 0) && (K % BK == 0) &&
                     (K / BK >= 4) && (ws_size >= need);
  if (ok256) {
    long n4 = xn / 4;
    quant_x_kernel<<<(int)((n4 + 255) / 256), 256, 0, stream>>>(x, xq, n4);
    dim3 grid(N / BN, M / BM);
    gemm256_kernel<<<grid, 512, 0, stream>>>(xq, wq, out, M, N, K);
  } else {
    dim3 grid(N / 128, M / 128);
    gemm_fused128_kernel<<<grid, 256, 0, stream>>>(x, wq, out, M, N, K);
  }
}

// Round 4
// 358.166 us; speedup vs baseline: 1.1765x; 1.0143x over previous
//
#include <hip/hip_runtime.h>
#include <hip/hip_bf16.h>
#include <cmath>
#include <cstdint>

// R4: rotated software pipeline on the verified R1 skeleton (single barrier/iter,
// counted vmcnt, st_16x32 swizzle, setprio). Changes vs R1:
//  - loop rotated: iter ends with {vmcnt(4), barrier, pre-issue group0 ds_reads
//    (b0..b3,a0,a1) of tile t+1} so the first read burst overlaps barrier
//    straggle + next iter's stage issue.
//  - remaining reads (a2..a7) issued in pairs BETWEEN MFMA clusters; compiler
//    emits counted lgkmcnt so each pair is in flight under 8 MFMAs (within-wave
//    ILP overlap of LDS-read and matrix pipe -- the serialization R3 measured).
//  - staging moved to tile t+2 (depth-2): prologue stages t0,t1 (8 in flight);
//    per-iter stage t+2; end-wait vmcnt(4) retires t+1 (tail vmcnt(0)).
// Race invariants:
//  - staging t+2 at iter t writes buf (t+2)&3 = (t-2)&3, last read at iter t-2,
//    drained 2 barriers ago (stronger than R1's 1-barrier distance).
//  - pre-read group0(t+1) pends across iter t's end barrier into iter t+1,
//    reading buf (t+1)&3; iter t+1 stages buf (t+3)&3 -- disjoint.
//  - tile t+1 residency at pre-read: own loads retired by vmcnt(4) (outstanding
//    was t+1(4)+t+2(4)=8), others' by the barrier.
//  - all barriers unconditional & uniform; every ds_read consumed by an MFMA
//    before the wave's next end-barrier (compiler data-dep lgkm waits).

#define AS1 __attribute__((address_space(1)))
#define AS3 __attribute__((address_space(3)))

typedef unsigned short u16;
typedef __bf16 bf16x8 __attribute__((ext_vector_type(8)));
typedef float f32x4 __attribute__((ext_vector_type(4)));
typedef unsigned short u16x4 __attribute__((ext_vector_type(4)));

#define BM 256
#define BN 256
#define BK 32
#define NBUF 4
// per-buf: A region 256*32 u16 (8192), B region 8192 -> buf stride 16384 u16

__device__ __forceinline__ u16 f2bf_rne(float f) {
  uint32_t u = __float_as_uint(f);
  u += 0x7FFFu + ((u >> 16) & 1u);
  return (u16)(u >> 16);
}

// activation ternary -> bf16 bits of {-0.5, 0, +0.5}
__device__ __forceinline__ u16 ter_x(float v) {
  double d = (double)v;
  return d > 0.33 ? (u16)0x3F00u : (d < -0.33 ? (u16)0xBF00u : (u16)0u);
}

// weight ternary -> fp32 {-0.6, 0, +0.6}
__device__ __forceinline__ float ter_w(float v) {
  double d = (double)v;
  return d > 0.2 ? 0.6f : (d < -0.2 ? -0.6f : 0.0f);
}

__global__ void quant_x_kernel(const float* __restrict__ x, u16* __restrict__ xq,
                               long n4) {
  long i = (long)blockIdx.x * blockDim.x + threadIdx.x;
  if (i >= n4) return;
  float4 v = ((const float4*)x)[i];
  u16x4 q;
  q.x = ter_x(v.x); q.y = ter_x(v.y); q.z = ter_x(v.z); q.w = ter_x(v.w);
  ((u16x4*)xq)[i] = q;
}

__global__ void quant_w_kernel(const float* __restrict__ w,
                               const float* __restrict__ rr,
                               u16* __restrict__ wq, long n4) {
  long i = (long)blockIdx.x * blockDim.x + threadIdx.x;
  if (i >= n4) return;
  float4 a = ((const float4*)w)[i];
  float4 b = ((const float4*)rr)[i];
  u16x4 q;
  q.x = f2bf_rne(ter_w(a.x) + b.x);
  q.y = f2bf_rne(ter_w(a.y) + b.y);
  q.z = f2bf_rne(ter_w(a.z) + b.z);
  q.w = f2bf_rne(ter_w(a.w) + b.w);
  ((u16x4*)wq)[i] = q;
}

// async 16B/lane global->LDS; LDS dest is wave-uniform base + lane*16
__device__ __forceinline__ void gld_lds16(const void* g, void* l) {
  __builtin_amdgcn_global_load_lds((AS1 void*)g, (AS3 void*)l, 16, 0, 0);
}

// C[m][n] = sum_k A[m][k] * B[n][k]  (both K-contiguous bf16; C fp32)
// Requires M%256==0, N%256==0, K%32==0, K/32>=4.
__global__ __launch_bounds__(512, 2) void gemm256_kernel(
    const u16* __restrict__ Aq, const u16* __restrict__ Bq,
    float* __restrict__ C, int M, int N, int K) {
  __shared__ u16 lds[NBUF * 16384];  // 128 KiB

  const int tid  = threadIdx.x;
  const int wid  = tid >> 6;
  const int lane = tid & 63;
  const int wm = wid >> 2;   // 0..1  (rows: wm*128)
  const int wn = wid & 3;    // 0..3  (cols: wn*64)

  const int m0 = blockIdx.y * BM;
  const int n0 = blockIdx.x * BN;

  // ---- staging addressing: per slot (2/region), wave covers 16 rows of 64B
  const int srow = wid * 16 + (lane >> 2);                    // 0..127 (+128 slot1)
  const int scol = ((lane & 3) * 8) ^ ((lane & 32) ? 16 : 0); // pre-swizzled src col
  const u16* pa = Aq + (size_t)(m0 + srow) * K + scol;
  const u16* pb = Bq + (size_t)(n0 + srow) * K + scol;
  const size_t slot1 = (size_t)128 * K;
  const int sd = wid * 512;  // wave's u16 offset within a region slot

  // ---- fragment read addressing (swizzled) ----
  const int fr  = lane & 15;
  const int fk  = (lane >> 4) * 8;
  const int col = fk ^ ((fr & 8) ? 16 : 0);
  const int aoff = (wm * 128 + fr) * 32 + col;         // + mt*512
  const int boff = 8192 + (wn * 64 + fr) * 32 + col;   // + ntl*512

  f32x4 acc[8][4] = {};
  const int nt = K / BK;

  // prologue: stage tiles 0,1 (8 loads/wave in flight)
#pragma unroll
  for (int T = 0; T < 2; ++T) {
    const int bb = T * 16384;
    const u16* at = pa + (size_t)T * BK;
    const u16* bt = pb + (size_t)T * BK;
    gld_lds16(at,         &lds[bb + sd]);
    gld_lds16(at + slot1, &lds[bb + sd + 4096]);
    gld_lds16(bt,         &lds[bb + 8192 + sd]);
    gld_lds16(bt + slot1, &lds[bb + 8192 + sd + 4096]);
  }
  asm volatile("s_waitcnt vmcnt(4)" ::: "memory");  // tile 0 (mine) retired
  __builtin_amdgcn_sched_barrier(0);
  __builtin_amdgcn_s_barrier();                     // tile 0 resident for all
  __builtin_amdgcn_sched_barrier(0);

  bf16x8 ag[8], bg[4];
  // pre-read group0 of tile 0
#pragma unroll
  for (int j = 0; j < 4; ++j) bg[j] = *(const bf16x8*)&lds[boff + j * 512];
  ag[0] = *(const bf16x8*)&lds[aoff];
  ag[1] = *(const bf16x8*)&lds[aoff + 512];

  for (int t = 0; t < nt; ++t) {
    const int rb = (t & 3) * 16384;

    // stage tile t+2 into buf (t+2)&3  (last read iter t-2)
    if (t + 2 < nt) {
      const int bb = ((t + 2) & 3) * 16384;
      const u16* at = pa + (size_t)(t + 2) * BK;
      const u16* bt = pb + (size_t)(t + 2) * BK;
      gld_lds16(at,         &lds[bb + sd]);
      gld_lds16(at + slot1, &lds[bb + sd + 4096]);
      gld_lds16(bt,         &lds[bb + 8192 + sd]);
      gld_lds16(bt + slot1, &lds[bb + 8192 + sd + 4096]);
    }
    __builtin_amdgcn_sched_barrier(0);

    // issue a2,a3; MFMA i=0,1 runs while they fly
    ag[2] = *(const bf16x8*)&lds[rb + aoff + 2 * 512];
    ag[3] = *(const bf16x8*)&lds[rb + aoff + 3 * 512];
    __builtin_amdgcn_sched_barrier(0);
    __builtin_amdgcn_s_setprio(1);
#pragma unroll
    for (int j = 0; j < 4; ++j)
      acc[0][j] = __builtin_amdgcn_mfma_f32_16x16x32_bf16(ag[0], bg[j], acc[0][j], 0, 0, 0);
#pragma unroll
    for (int j = 0; j < 4; ++j)
      acc[1][j] = __builtin_amdgcn_mfma_f32_16x16x32_bf16(ag[1], bg[j], acc[1][j], 0, 0, 0);
    __builtin_amdgcn_s_setprio(0);
    __builtin_amdgcn_sched_barrier(0);

    ag[4] = *(const bf16x8*)&lds[rb + aoff + 4 * 512];
    ag[5] = *(const bf16x8*)&lds[rb + aoff + 5 * 512];
    __builtin_amdgcn_sched_barrier(0);
    __builtin_amdgcn_s_setprio(1);
#pragma unroll
    for (int j = 0; j < 4; ++j)
      acc[2][j] = __builtin_amdgcn_mfma_f32_16x16x32_bf16(ag[2], bg[j], acc[2][j], 0, 0, 0);
#pragma unroll
    for (int j = 0; j < 4; ++j)
      acc[3][j] = __builtin_amdgcn_mfma_f32_16x16x32_bf16(ag[3], bg[j], acc[3][j], 0, 0, 0);
    __builtin_amdgcn_s_setprio(0);
    __builtin_amdgcn_sched_barrier(0);

    ag[6] = *(const bf16x8*)&lds[rb + aoff + 6 * 512];
    ag[7] = *(const bf16x8*)&lds[rb + aoff + 7 * 512];
    __builtin_amdgcn_sched_barrier(0);
    __builtin_amdgcn_s_setprio(1);
#pragma unroll
    for (int j = 0; j < 4; ++j)
      acc[4][j] = __builtin_amdgcn_mfma_f32_16x16x32_bf16(ag[4], bg[j], acc[4][j], 0, 0, 0);
#pragma unroll
    for (int j = 0; j < 4; ++j)
      acc[5][j] = __builtin_amdgcn_mfma_f32_16x16x32_bf16(ag[5], bg[j], acc[5][j], 0, 0, 0);
    __builtin_amdgcn_s_setprio(0);
    __builtin_amdgcn_sched_barrier(0);
    __builtin_amdgcn_s_setprio(1);
#pragma unroll
    for (int j = 0; j < 4; ++j)
      acc[6][j] = __builtin_amdgcn_mfma_f32_16x16x32_bf16(ag[6], bg[j], acc[6][j], 0, 0, 0);
#pragma unroll
    for (int j = 0; j < 4; ++j)
      acc[7][j] = __builtin_amdgcn_mfma_f32_16x16x32_bf16(ag[7], bg[j], acc[7][j], 0, 0, 0);
    __builtin_amdgcn_s_setprio(0);
    __builtin_amdgcn_sched_barrier(0);

    // end-of-iter: confirm tile t+1, then pre-issue its group0 reads
    if (t < nt - 2) asm volatile("s_waitcnt vmcnt(4)" ::: "memory");
    else            asm volatile("s_waitcnt vmcnt(0)" ::: "memory");
    __builtin_amdgcn_sched_barrier(0);
    __builtin_amdgcn_s_barrier();
    __builtin_amdgcn_sched_barrier(0);
    if (t + 1 < nt) {
      const int rb2 = ((t + 1) & 3) * 16384;
#pragma unroll
      for (int j = 0; j < 4; ++j) bg[j] = *(const bf16x8*)&lds[rb2 + boff + j * 512];
      ag[0] = *(const bf16x8*)&lds[rb2 + aoff];
      ag[1] = *(const bf16x8*)&lds[rb2 + aoff + 512];
    }
    __builtin_amdgcn_sched_barrier(0);
  }

  // C/D layout: row = (lane>>4)*4 + reg, col = lane&15  [measured m89/m91]
  const int om = m0 + wm * 128 + (lane >> 4) * 4;
  const int on = n0 + wn * 64 + (lane & 15);
#pragma unroll
  for (int i = 0; i < 8; ++i)
#pragma unroll
    for (int j = 0; j < 4; ++j)
#pragma unroll
      for (int r = 0; r < 4; ++r)
        C[(size_t)(om + i * 16 + r) * N + (on + j * 16)] = acc[i][j][r];
}

// ---- fallback (workspace too small): old fused 128x128 kernel, verified R0 ----
__global__ __launch_bounds__(256) void gemm_fused128_kernel(
    const float* __restrict__ Xf, const u16* __restrict__ Bq,
    float* __restrict__ C, int M, int N, int K) {
  __shared__ u16 As[128 * 64];
  __shared__ u16 Bs[128 * 64];

  const int tid  = threadIdx.x;
  const int wid  = tid >> 6;
  const int lane = tid & 63;
  const int m0 = blockIdx.y * 128;
  const int n0 = blockIdx.x * 128;
  const int r8 = lane >> 3;
  const int c8 = (lane & 7) * 8;
  const int mw = (wid >> 1) * 64;
  const int nw = (wid & 1) * 64;
  const int fr = lane & 15;
  const int fk = (lane >> 4) * 8;

  f32x4 acc[4][4] = {};

  for (int k0 = 0; k0 < K; k0 += 64) {
#pragma unroll
    for (int t = 0; t < 4; ++t) {
      const int rbase = wid * 32 + t * 8;
      gld_lds16(Bq + (size_t)(n0 + rbase + r8) * K + k0 + c8, &Bs[rbase * 64]);
    }
#pragma unroll
    for (int it = 0; it < 8; ++it) {
      const int idx = it * 256 + tid;
      const int row = idx >> 4;
      const int c4  = (idx & 15) * 4;
      const float4 v = *(const float4*)&Xf[(size_t)(m0 + row) * K + k0 + c4];
      u16x4 q;
      q.x = ter_x(v.x); q.y = ter_x(v.y); q.z = ter_x(v.z); q.w = ter_x(v.w);
      *(u16x4*)&As[row * 64 + c4] = q;
    }
    __syncthreads();

#pragma unroll
    for (int kk = 0; kk < 64; kk += 32) {
      bf16x8 a[4], b[4];
#pragma unroll
      for (int i = 0; i < 4; ++i)
        a[i] = *(const bf16x8*)&As[(mw + i * 16 + fr) * 64 + kk + fk];
#pragma unroll
      for (int j = 0; j < 4; ++j)
        b[j] = *(const bf16x8*)&Bs[(nw + j * 16 + fr) * 64 + kk + fk];
#pragma unroll
      for (int i = 0; i < 4; ++i)
#pragma unroll
        for (int j = 0; j < 4; ++j)
          acc[i][j] =
              __builtin_amdgcn_mfma_f32_16x16x32_bf16(a[i], b[j], acc[i][j], 0, 0, 0);
    }
    __syncthreads();
  }

  const int om = m0 + mw + (lane >> 4) * 4;
  const int on = n0 + nw + (lane & 15);
#pragma unroll
  for (int i = 0; i < 4; ++i)
#pragma unroll
    for (int j = 0; j < 4; ++j)
#pragma unroll
      for (int r = 0; r < 4; ++r)
        C[(size_t)(om + i * 16 + r) * N + (on + j * 16)] = acc[i][j][r];
}

extern "C" void kernel_launch(void* const* d_in, const int* in_sizes, int n_in,
                              void* d_out, int out_size, void* d_ws, size_t ws_size,
                              hipStream_t stream) {
  const float* x  = (const float*)d_in[0];
  const float* w  = (const float*)d_in[1];
  const float* rr = (const float*)d_in[2];
  float* out = (float*)d_out;

  const long xn = (long)in_sizes[0];
  const long wn = (long)in_sizes[1];
  const int K = (int)llround(std::sqrt((double)wn));  // weight is [D,D]
  const int N = K;
  const int M = (int)(xn / K);

  u16* wq = (u16*)d_ws;
  u16* xq = (u16*)d_ws + (size_t)N * K;
  const size_t need = ((size_t)M * K + (size_t)N * K) * sizeof(u16);

  {
    long n4 = wn / 4;
    quant_w_kernel<<<(int)((n4 + 255) / 256), 256, 0, stream>>>(w, rr, wq, n4);
  }

  const bool ok256 = (M % BM == 0) && (N % BN == 0) && (K % BK == 0) &&
                     (K / BK >= 4) && (ws_size >= need);
  if (ok256) {
    long n4 = xn / 4;
    quant_x_kernel<<<(int)((n4 + 255) / 256), 256, 0, stream>>>(x, xq, n4);
    dim3 grid(N / BN, M / BM);
    gemm256_kernel<<<grid, 512, 0, stream>>>(xq, wq, out, M, N, K);
  } else {
    dim3 grid(N / 128, M / 128);
    gemm_fused128_kernel<<<grid, 256, 0, stream>>>(x, wq, out, M, N, K);
  }
}